// Round 2
// baseline (172.582 us; speedup 1.0000x reference)
//
#include <hip/hip_runtime.h>
#include <hip/hip_bf16.h>

// SeFT reduced computation (sum(softmax)==1 kills the attention/sh/sg branches):
//   h1[m]  = relu(xf(64x3072) @ ah1_w[m](3072x1024) + ah1_b[m])
//   r[:,m] = h1[m] @ ah2_w[m](1024x128)            (bias+relu deferred to final)
//   out    = sigmoid(relu(relu(relu(r+b2) @ f1+b)@f2+b)@f3+b)
// 3 kernels: gemm1 (bf16 MFMA, split-K=4, 2-deep prefetch, reads x f32 directly),
// gemm2 (fused partial-reduce + per-thread full-k-slice dot, emits r-partials,
// also converts f1w/f2w to bf16), final (fused MLP).

#define K1   3072
#define N1   1024
#define KSPL 4
#define KRNG 768      // K1/KSPL
#define BK   32
#define NIT  24       // KRNG/BK
#define BN   32

typedef short bf16x8 __attribute__((ext_vector_type(8)));
typedef float f32x4  __attribute__((ext_vector_type(4)));
typedef unsigned short ushort4v __attribute__((ext_vector_type(4)));

__device__ __forceinline__ unsigned short f2b(float f) {
  unsigned int u = __float_as_uint(f);
  return (unsigned short)((u + 0x7FFFu + ((u >> 16) & 1u)) >> 16);   // RNE
}
__device__ __forceinline__ float b2f(unsigned short b) {
  return __uint_as_float(((unsigned int)b) << 16);
}
__device__ __forceinline__ float relu(float v) { return v > 0.f ? v : 0.f; }

// bf16 B-tile LDS chunk swizzle (verified layout from the passing round)
__device__ __forceinline__ int bchunk(int c, int q) {
  return c * 4 + (q ^ (c & 3) ^ ((c >> 2) & 3));
}

// ---------------- kernel 1: big GEMM, bf16 MFMA, split-K, 2-deep prefetch ----
__global__ __launch_bounds__(256, 2) void k_gemm1(
    const float* __restrict__ x,            // [64][3072] f32
    const float* __restrict__ W,            // ah1_w [4][3072][1024]
    float* __restrict__ part)               // [KSPL][4][64][1024]
{
  __shared__ __align__(16) unsigned short Bt[BN * BK];  // 2KB, chunk-addressed

  const int nt = blockIdx.x, ks = blockIdx.y, h = blockIdx.z;
  const int tid = threadIdx.x;
  const int kbase = ks * KRNG;
  const int skr = tid >> 3;           // staging local k-row 0..31
  const int sc4 = (tid & 7) * 4;      // staging col quad
  const int w = tid >> 6, lane = tid & 63, lr = lane & 15, lkg = lane >> 4;

  const float* Wp = W + (size_t)h * K1 * N1 + (size_t)(kbase + skr) * N1
                      + nt * BN + sc4;
  const float* Ap = x + (size_t)(16 * w + lr) * K1 + kbase + lkg * 8;

  f32x4 acc0 = {0.f, 0.f, 0.f, 0.f}, acc1 = {0.f, 0.f, 0.f, 0.f};

  // 2-deep register prefetch (named buffers: no runtime-indexed arrays)
  float4 bwA = *(const float4*)(Wp);
  float4 axA = *(const float4*)(Ap);
  float4 ayA = *(const float4*)(Ap + 4);
  float4 bwB = *(const float4*)(Wp + (size_t)BK * N1);
  float4 axB = *(const float4*)(Ap + BK);
  float4 ayB = *(const float4*)(Ap + BK + 4);

#define G1_BODY(BW, AX, AY, IT)                                            \
  {                                                                        \
    const int q_ = skr >> 3, klo_ = skr & 7;                               \
    Bt[bchunk(sc4 + 0, q_) * 8 + klo_] = f2b(BW.x);                        \
    Bt[bchunk(sc4 + 1, q_) * 8 + klo_] = f2b(BW.y);                        \
    Bt[bchunk(sc4 + 2, q_) * 8 + klo_] = f2b(BW.z);                        \
    Bt[bchunk(sc4 + 3, q_) * 8 + klo_] = f2b(BW.w);                        \
    __syncthreads();                                                       \
    bf16x8 af;                                                             \
    af[0] = (short)f2b(AX.x); af[1] = (short)f2b(AX.y);                    \
    af[2] = (short)f2b(AX.z); af[3] = (short)f2b(AX.w);                    \
    af[4] = (short)f2b(AY.x); af[5] = (short)f2b(AY.y);                    \
    af[6] = (short)f2b(AY.z); af[7] = (short)f2b(AY.w);                    \
    bf16x8 bf0 = *(const bf16x8*)&Bt[bchunk(lr,      lkg) * 8];            \
    bf16x8 bf1 = *(const bf16x8*)&Bt[bchunk(16 + lr, lkg) * 8];            \
    if ((IT) + 2 < NIT) {                                                  \
      BW = *(const float4*)(Wp + (size_t)((IT) + 2) * BK * N1);            \
      AX = *(const float4*)(Ap + ((IT) + 2) * BK);                         \
      AY = *(const float4*)(Ap + ((IT) + 2) * BK + 4);                     \
    }                                                                      \
    acc0 = __builtin_amdgcn_mfma_f32_16x16x32_bf16(af, bf0, acc0, 0, 0, 0);\
    acc1 = __builtin_amdgcn_mfma_f32_16x16x32_bf16(af, bf1, acc1, 0, 0, 0);\
    __syncthreads();                                                       \
  }

  for (int it = 0; it < NIT; it += 2) {
    G1_BODY(bwA, axA, ayA, it);
    G1_BODY(bwB, axB, ayB, it + 1);
  }
#undef G1_BODY

  // C-partial store. D layout: col = lane&15, row = (lane>>4)*4 + i
  float* P = part + ((size_t)ks * 4 + h) * (64 * N1)
                  + (size_t)(16 * w + lkg * 4) * N1 + nt * BN + lr;
#pragma unroll
  for (int i = 0; i < 4; ++i) {
    P[(size_t)i * N1]      = acc0[i];
    P[(size_t)i * N1 + 16] = acc1[i];
  }
}

// -------- kernel 2: fused reduce+bias+relu, GEMM2 k-slice, weight convert ----
__global__ __launch_bounds__(256) void k_gemm2(
    const float* __restrict__ part,   // [4][4][64][1024]
    const float* __restrict__ b1,     // ah1_b [4][1024]
    const float* __restrict__ W2,     // ah2_w [4][1024][128]
    const float* __restrict__ f1w,    // [512][256] f32
    const float* __restrict__ f2w,    // [256][64]  f32
    float* __restrict__ rpart,        // [8][64][512]
    unsigned short* __restrict__ f1wb,
    unsigned short* __restrict__ f2wb)
{
  __shared__ float hl[8][128];   // h1 rows for this (b-group, k-slice)
  const int bg = blockIdx.x, kslc = blockIdx.y, h = blockIdx.z;
  const int t = threadIdx.x;

  {  // reduce 4 split-K partials + bias + relu -> hl
    const int bl = t >> 5, kq = t & 31;
    const int brow = bg * 8 + bl, kg = kslc * 128 + kq * 4;
    float4 s = {0.f, 0.f, 0.f, 0.f};
#pragma unroll
    for (int ksp = 0; ksp < 4; ++ksp) {
      float4 p = *(const float4*)&part[(((size_t)ksp * 4 + h) * 64 + brow) * 1024 + kg];
      s.x += p.x; s.y += p.y; s.z += p.z; s.w += p.w;
    }
    float4 bb = *(const float4*)&b1[h * 1024 + kg];
    float4 o;
    o.x = relu(s.x + bb.x); o.y = relu(s.y + bb.y);
    o.z = relu(s.z + bb.z); o.w = relu(s.w + bb.w);
    *(float4*)&hl[bl][kq * 4] = o;
  }
  __syncthreads();

  // each thread owns (b-row bl, d-quad dg) over the FULL 128-k slice:
  // no second reduction needed; write one r-partial per k-slice.
  const int bl = t >> 5, dg = t & 31;
  const float* Wp = W2 + (size_t)h * 131072 + (size_t)(kslc * 128) * 128 + dg * 4;
  float a0 = 0.f, a1 = 0.f, a2 = 0.f, a3 = 0.f;
#pragma unroll 4
  for (int kk4 = 0; kk4 < 32; ++kk4) {
    float4 h4 = *(const float4*)&hl[bl][kk4 * 4];
    float4 w0 = *(const float4*)(Wp + (size_t)(kk4 * 4 + 0) * 128);
    float4 w1 = *(const float4*)(Wp + (size_t)(kk4 * 4 + 1) * 128);
    float4 w2 = *(const float4*)(Wp + (size_t)(kk4 * 4 + 2) * 128);
    float4 w3 = *(const float4*)(Wp + (size_t)(kk4 * 4 + 3) * 128);
    a0 += h4.x * w0.x; a1 += h4.x * w0.y; a2 += h4.x * w0.z; a3 += h4.x * w0.w;
    a0 += h4.y * w1.x; a1 += h4.y * w1.y; a2 += h4.y * w1.z; a3 += h4.y * w1.w;
    a0 += h4.z * w2.x; a1 += h4.z * w2.y; a2 += h4.z * w2.z; a3 += h4.z * w2.w;
    a0 += h4.w * w3.x; a1 += h4.w * w3.y; a2 += h4.w * w3.z; a3 += h4.w * w3.w;
  }
  {
    float4 o = {a0, a1, a2, a3};
    *(float4*)(rpart + ((size_t)kslc * 64 + (bg * 8 + bl)) * 512 + h * 128 + dg * 4) = o;
  }

  // side job: convert final-MLP weights to bf16 for k_final (stream-ordered)
  const int cid = bg * 8 + kslc;               // 0..63
  if (h == 0) {                                // f1w: 64*256*8 = 131072 elems
    const int base = (cid * 256 + t) * 8;
    float4 v0 = *(const float4*)(f1w + base);
    float4 v1 = *(const float4*)(f1w + base + 4);
    ushort4v o0, o1;
    o0.x = f2b(v0.x); o0.y = f2b(v0.y); o0.z = f2b(v0.z); o0.w = f2b(v0.w);
    o1.x = f2b(v1.x); o1.y = f2b(v1.y); o1.z = f2b(v1.z); o1.w = f2b(v1.w);
    *(ushort4v*)(f1wb + base) = o0;
    *(ushort4v*)(f1wb + base + 4) = o1;
  } else if (h == 1) {                         // f2w: 64*256 = 16384 elems
    const int idx = cid * 256 + t;
    f2wb[idx] = f2b(f2w[idx]);
  }
}

// ---------------- kernel 3: fused final MLP + sigmoid ----------------
__global__ __launch_bounds__(512) void k_final(
    const float* __restrict__ rpart,  // [8][64][512]
    const float* __restrict__ b2,     // ah2_b flat [512]
    const unsigned short* __restrict__ f1wb, const float* __restrict__ f1b,
    const unsigned short* __restrict__ f2wb, const float* __restrict__ f2bv,
    const float* __restrict__ f3w, const float* __restrict__ f3b,
    float* __restrict__ out)
{
  const int b = blockIdx.x, t = threadIdx.x;
  __shared__ float rr[512];
  __shared__ float y1p[2][256];
  __shared__ float y1[256];
  __shared__ float y2p[4][64];
  __shared__ float y2[64];

  {  // r = sum of 8 k-slice partials, + bias, relu
    float s = 0.f;
#pragma unroll
    for (int sl = 0; sl < 8; ++sl) s += rpart[((size_t)sl * 64 + b) * 512 + t];
    rr[t] = relu(s + b2[t]);
  }
  __syncthreads();

  {  // y1 = relu(rr @ f1w + f1b), K=512 split over 2, bf16 weights
    const int j = t & 255, kh = t >> 8;
    const unsigned short* W = f1wb + kh * 256 * 256 + j;
    const float* rv = rr + kh * 256;
    float a0 = 0.f, a1 = 0.f, a2 = 0.f, a3 = 0.f;
#pragma unroll 4
    for (int k = 0; k < 256; k += 4) {
      a0 += rv[k + 0] * b2f(W[(size_t)(k + 0) * 256]);
      a1 += rv[k + 1] * b2f(W[(size_t)(k + 1) * 256]);
      a2 += rv[k + 2] * b2f(W[(size_t)(k + 2) * 256]);
      a3 += rv[k + 3] * b2f(W[(size_t)(k + 3) * 256]);
    }
    y1p[kh][j] = a0 + a1 + a2 + a3;
  }
  __syncthreads();
  if (t < 256) y1[t] = relu(y1p[0][t] + y1p[1][t] + f1b[t]);
  __syncthreads();

  if (t < 256) {  // y2 = relu(y1 @ f2w + f2b), K=256 split over 4
    const int j = t & 63, kh = t >> 6;
    const unsigned short* W = f2wb + kh * 64 * 64 + j;
    const float* yv = y1 + kh * 64;
    float a = 0.f;
#pragma unroll 4
    for (int k = 0; k < 64; ++k) a += yv[k] * b2f(W[(size_t)k * 64]);
    y2p[kh][j] = a;
  }
  __syncthreads();
  if (t < 64) y2[t] = relu(y2p[0][t] + y2p[1][t] + y2p[2][t] + y2p[3][t] + f2bv[t]);
  __syncthreads();

  if (t == 0) {
    float s = f3b[0];
#pragma unroll 8
    for (int k = 0; k < 64; ++k) s += y2[k] * f3w[k];
    out[b] = 1.f / (1.f + expf(-s));
  }
}

extern "C" void kernel_launch(void* const* d_in, const int* in_sizes, int n_in,
                              void* d_out, int out_size, void* d_ws, size_t ws_size,
                              hipStream_t stream) {
  (void)in_sizes; (void)n_in; (void)out_size; (void)ws_size;
  const float* x     = (const float*)d_in[0];
  const float* ah1_w = (const float*)d_in[12];
  const float* ah1_b = (const float*)d_in[13];
  const float* ah2_w = (const float*)d_in[14];
  const float* ah2_b = (const float*)d_in[15];
  const float* f1w   = (const float*)d_in[16];
  const float* f1b   = (const float*)d_in[17];
  const float* f2w   = (const float*)d_in[18];
  const float* f2b_  = (const float*)d_in[19];
  const float* f3w   = (const float*)d_in[20];
  const float* f3b   = (const float*)d_in[21];
  float* out = (float*)d_out;

  char* ws = (char*)d_ws;
  float* part = (float*)ws;                                   // 4 MB
  float* rpart = (float*)(ws + 4194304);                      // 1 MB
  unsigned short* f1wb = (unsigned short*)(ws + 5242880);     // 256 KB
  unsigned short* f2wb = (unsigned short*)(ws + 5505024);     // 32 KB

  k_gemm1<<<dim3(32, KSPL, 4), 256, 0, stream>>>(x, ah1_w, part);
  k_gemm2<<<dim3(8, 8, 4), 256, 0, stream>>>(part, ah1_b, ah2_w, f1w, f2w,
                                             rpart, f1wb, f2wb);
  k_final<<<64, 512, 0, stream>>>(rpart, ah2_b, f1wb, f1b, f2wb, f2b_,
                                  f3w, f3b, out);
}

// Round 3
// 163.985 us; speedup vs baseline: 1.0524x; 1.0524x over previous
//
#include <hip/hip_runtime.h>
#include <hip/hip_bf16.h>

// SeFT reduced computation (sum(softmax)==1 kills the attention/sh/sg branches):
//   h1[m]  = relu(xf(64x3072) @ ah1_w[m](3072x1024) + ah1_b[m])
//   r[:,m] = h1[m] @ ah2_w[m](1024x128)            (bias+relu deferred to final)
//   out    = sigmoid(relu(relu(relu(r+b2) @ f1+b)@f2+b)@f3+b)
// Round 3: KSPL 4->8 (1024 blocks = 4/CU) to test whether gemm1 was
// latency-bound at 2 blocks/CU. Everything else unchanged from R2.

#define K1   3072
#define N1   1024
#define KSPL 8
#define KRNG 384      // K1/KSPL
#define BK   32
#define NIT  12       // KRNG/BK
#define BN   32

typedef short bf16x8 __attribute__((ext_vector_type(8)));
typedef float f32x4  __attribute__((ext_vector_type(4)));
typedef unsigned short ushort4v __attribute__((ext_vector_type(4)));

__device__ __forceinline__ unsigned short f2b(float f) {
  unsigned int u = __float_as_uint(f);
  return (unsigned short)((u + 0x7FFFu + ((u >> 16) & 1u)) >> 16);   // RNE
}
__device__ __forceinline__ float b2f(unsigned short b) {
  return __uint_as_float(((unsigned int)b) << 16);
}
__device__ __forceinline__ float relu(float v) { return v > 0.f ? v : 0.f; }

// bf16 B-tile LDS chunk swizzle (verified layout from the passing rounds)
__device__ __forceinline__ int bchunk(int c, int q) {
  return c * 4 + (q ^ (c & 3) ^ ((c >> 2) & 3));
}

// ---------------- kernel 1: big GEMM, bf16 MFMA, split-K=8, 2-deep prefetch --
__global__ __launch_bounds__(256, 2) void k_gemm1(
    const float* __restrict__ x,            // [64][3072] f32
    const float* __restrict__ W,            // ah1_w [4][3072][1024]
    float* __restrict__ part)               // [KSPL][4][64][1024]
{
  __shared__ __align__(16) unsigned short Bt[BN * BK];  // 2KB, chunk-addressed

  const int nt = blockIdx.x, ks = blockIdx.y, h = blockIdx.z;
  const int tid = threadIdx.x;
  const int kbase = ks * KRNG;
  const int skr = tid >> 3;           // staging local k-row 0..31
  const int sc4 = (tid & 7) * 4;      // staging col quad
  const int w = tid >> 6, lane = tid & 63, lr = lane & 15, lkg = lane >> 4;

  const float* Wp = W + (size_t)h * K1 * N1 + (size_t)(kbase + skr) * N1
                      + nt * BN + sc4;
  const float* Ap = x + (size_t)(16 * w + lr) * K1 + kbase + lkg * 8;

  f32x4 acc0 = {0.f, 0.f, 0.f, 0.f}, acc1 = {0.f, 0.f, 0.f, 0.f};

  // 2-deep register prefetch (named buffers: no runtime-indexed arrays)
  float4 bwA = *(const float4*)(Wp);
  float4 axA = *(const float4*)(Ap);
  float4 ayA = *(const float4*)(Ap + 4);
  float4 bwB = *(const float4*)(Wp + (size_t)BK * N1);
  float4 axB = *(const float4*)(Ap + BK);
  float4 ayB = *(const float4*)(Ap + BK + 4);

#define G1_BODY(BW, AX, AY, IT)                                            \
  {                                                                        \
    const int q_ = skr >> 3, klo_ = skr & 7;                               \
    Bt[bchunk(sc4 + 0, q_) * 8 + klo_] = f2b(BW.x);                        \
    Bt[bchunk(sc4 + 1, q_) * 8 + klo_] = f2b(BW.y);                        \
    Bt[bchunk(sc4 + 2, q_) * 8 + klo_] = f2b(BW.z);                        \
    Bt[bchunk(sc4 + 3, q_) * 8 + klo_] = f2b(BW.w);                        \
    __syncthreads();                                                       \
    bf16x8 af;                                                             \
    af[0] = (short)f2b(AX.x); af[1] = (short)f2b(AX.y);                    \
    af[2] = (short)f2b(AX.z); af[3] = (short)f2b(AX.w);                    \
    af[4] = (short)f2b(AY.x); af[5] = (short)f2b(AY.y);                    \
    af[6] = (short)f2b(AY.z); af[7] = (short)f2b(AY.w);                    \
    bf16x8 bf0 = *(const bf16x8*)&Bt[bchunk(lr,      lkg) * 8];            \
    bf16x8 bf1 = *(const bf16x8*)&Bt[bchunk(16 + lr, lkg) * 8];            \
    if ((IT) + 2 < NIT) {                                                  \
      BW = *(const float4*)(Wp + (size_t)((IT) + 2) * BK * N1);            \
      AX = *(const float4*)(Ap + ((IT) + 2) * BK);                         \
      AY = *(const float4*)(Ap + ((IT) + 2) * BK + 4);                     \
    }                                                                      \
    acc0 = __builtin_amdgcn_mfma_f32_16x16x32_bf16(af, bf0, acc0, 0, 0, 0);\
    acc1 = __builtin_amdgcn_mfma_f32_16x16x32_bf16(af, bf1, acc1, 0, 0, 0);\
    __syncthreads();                                                       \
  }

  for (int it = 0; it < NIT; it += 2) {
    G1_BODY(bwA, axA, ayA, it);
    G1_BODY(bwB, axB, ayB, it + 1);
  }
#undef G1_BODY

  // C-partial store. D layout: col = lane&15, row = (lane>>4)*4 + i
  float* P = part + ((size_t)ks * 4 + h) * (64 * N1)
                  + (size_t)(16 * w + lkg * 4) * N1 + nt * BN + lr;
#pragma unroll
  for (int i = 0; i < 4; ++i) {
    P[(size_t)i * N1]      = acc0[i];
    P[(size_t)i * N1 + 16] = acc1[i];
  }
}

// -------- kernel 2: fused reduce+bias+relu, GEMM2 k-slice, weight convert ----
__global__ __launch_bounds__(256) void k_gemm2(
    const float* __restrict__ part,   // [8][4][64][1024]
    const float* __restrict__ b1,     // ah1_b [4][1024]
    const float* __restrict__ W2,     // ah2_w [4][1024][128]
    const float* __restrict__ f1w,    // [512][256] f32
    const float* __restrict__ f2w,    // [256][64]  f32
    float* __restrict__ rpart,        // [8][64][512]
    unsigned short* __restrict__ f1wb,
    unsigned short* __restrict__ f2wb)
{
  __shared__ float hl[8][128];   // h1 rows for this (b-group, k-slice)
  const int bg = blockIdx.x, kslc = blockIdx.y, h = blockIdx.z;
  const int t = threadIdx.x;

  {  // reduce 8 split-K partials + bias + relu -> hl
    const int bl = t >> 5, kq = t & 31;
    const int brow = bg * 8 + bl, kg = kslc * 128 + kq * 4;
    float4 s = {0.f, 0.f, 0.f, 0.f};
#pragma unroll
    for (int ksp = 0; ksp < KSPL; ++ksp) {
      float4 p = *(const float4*)&part[(((size_t)ksp * 4 + h) * 64 + brow) * 1024 + kg];
      s.x += p.x; s.y += p.y; s.z += p.z; s.w += p.w;
    }
    float4 bb = *(const float4*)&b1[h * 1024 + kg];
    float4 o;
    o.x = relu(s.x + bb.x); o.y = relu(s.y + bb.y);
    o.z = relu(s.z + bb.z); o.w = relu(s.w + bb.w);
    *(float4*)&hl[bl][kq * 4] = o;
  }
  __syncthreads();

  // each thread owns (b-row bl, d-quad dg) over the FULL 128-k slice:
  // no second reduction needed; write one r-partial per k-slice.
  const int bl = t >> 5, dg = t & 31;
  const float* Wp = W2 + (size_t)h * 131072 + (size_t)(kslc * 128) * 128 + dg * 4;
  float a0 = 0.f, a1 = 0.f, a2 = 0.f, a3 = 0.f;
#pragma unroll 4
  for (int kk4 = 0; kk4 < 32; ++kk4) {
    float4 h4 = *(const float4*)&hl[bl][kk4 * 4];
    float4 w0 = *(const float4*)(Wp + (size_t)(kk4 * 4 + 0) * 128);
    float4 w1 = *(const float4*)(Wp + (size_t)(kk4 * 4 + 1) * 128);
    float4 w2 = *(const float4*)(Wp + (size_t)(kk4 * 4 + 2) * 128);
    float4 w3 = *(const float4*)(Wp + (size_t)(kk4 * 4 + 3) * 128);
    a0 += h4.x * w0.x; a1 += h4.x * w0.y; a2 += h4.x * w0.z; a3 += h4.x * w0.w;
    a0 += h4.y * w1.x; a1 += h4.y * w1.y; a2 += h4.y * w1.z; a3 += h4.y * w1.w;
    a0 += h4.z * w2.x; a1 += h4.z * w2.y; a2 += h4.z * w2.z; a3 += h4.z * w2.w;
    a0 += h4.w * w3.x; a1 += h4.w * w3.y; a2 += h4.w * w3.z; a3 += h4.w * w3.w;
  }
  {
    float4 o = {a0, a1, a2, a3};
    *(float4*)(rpart + ((size_t)kslc * 64 + (bg * 8 + bl)) * 512 + h * 128 + dg * 4) = o;
  }

  // side job: convert final-MLP weights to bf16 for k_final (stream-ordered)
  const int cid = bg * 8 + kslc;               // 0..63
  if (h == 0) {                                // f1w: 64*256*8 = 131072 elems
    const int base = (cid * 256 + t) * 8;
    float4 v0 = *(const float4*)(f1w + base);
    float4 v1 = *(const float4*)(f1w + base + 4);
    ushort4v o0, o1;
    o0.x = f2b(v0.x); o0.y = f2b(v0.y); o0.z = f2b(v0.z); o0.w = f2b(v0.w);
    o1.x = f2b(v1.x); o1.y = f2b(v1.y); o1.z = f2b(v1.z); o1.w = f2b(v1.w);
    *(ushort4v*)(f1wb + base) = o0;
    *(ushort4v*)(f1wb + base + 4) = o1;
  } else if (h == 1) {                         // f2w: 64*256 = 16384 elems
    const int idx = cid * 256 + t;
    f2wb[idx] = f2b(f2w[idx]);
  }
}

// ---------------- kernel 3: fused final MLP + sigmoid ----------------
__global__ __launch_bounds__(512) void k_final(
    const float* __restrict__ rpart,  // [8][64][512]
    const float* __restrict__ b2,     // ah2_b flat [512]
    const unsigned short* __restrict__ f1wb, const float* __restrict__ f1b,
    const unsigned short* __restrict__ f2wb, const float* __restrict__ f2bv,
    const float* __restrict__ f3w, const float* __restrict__ f3b,
    float* __restrict__ out)
{
  const int b = blockIdx.x, t = threadIdx.x;
  __shared__ float rr[512];
  __shared__ float y1p[2][256];
  __shared__ float y1[256];
  __shared__ float y2p[4][64];
  __shared__ float y2[64];

  {  // r = sum of 8 k-slice partials, + bias, relu
    float s = 0.f;
#pragma unroll
    for (int sl = 0; sl < 8; ++sl) s += rpart[((size_t)sl * 64 + b) * 512 + t];
    rr[t] = relu(s + b2[t]);
  }
  __syncthreads();

  {  // y1 = relu(rr @ f1w + f1b), K=512 split over 2, bf16 weights
    const int j = t & 255, kh = t >> 8;
    const unsigned short* W = f1wb + kh * 256 * 256 + j;
    const float* rv = rr + kh * 256;
    float a0 = 0.f, a1 = 0.f, a2 = 0.f, a3 = 0.f;
#pragma unroll 4
    for (int k = 0; k < 256; k += 4) {
      a0 += rv[k + 0] * b2f(W[(size_t)(k + 0) * 256]);
      a1 += rv[k + 1] * b2f(W[(size_t)(k + 1) * 256]);
      a2 += rv[k + 2] * b2f(W[(size_t)(k + 2) * 256]);
      a3 += rv[k + 3] * b2f(W[(size_t)(k + 3) * 256]);
    }
    y1p[kh][j] = a0 + a1 + a2 + a3;
  }
  __syncthreads();
  if (t < 256) y1[t] = relu(y1p[0][t] + y1p[1][t] + f1b[t]);
  __syncthreads();

  if (t < 256) {  // y2 = relu(y1 @ f2w + f2b), K=256 split over 4
    const int j = t & 63, kh = t >> 6;
    const unsigned short* W = f2wb + kh * 64 * 64 + j;
    const float* yv = y1 + kh * 64;
    float a = 0.f;
#pragma unroll 4
    for (int k = 0; k < 64; ++k) a += yv[k] * b2f(W[(size_t)k * 64]);
    y2p[kh][j] = a;
  }
  __syncthreads();
  if (t < 64) y2[t] = relu(y2p[0][t] + y2p[1][t] + y2p[2][t] + y2p[3][t] + f2bv[t]);
  __syncthreads();

  if (t == 0) {
    float s = f3b[0];
#pragma unroll 8
    for (int k = 0; k < 64; ++k) s += y2[k] * f3w[k];
    out[b] = 1.f / (1.f + expf(-s));
  }
}

extern "C" void kernel_launch(void* const* d_in, const int* in_sizes, int n_in,
                              void* d_out, int out_size, void* d_ws, size_t ws_size,
                              hipStream_t stream) {
  (void)in_sizes; (void)n_in; (void)out_size; (void)ws_size;
  const float* x     = (const float*)d_in[0];
  const float* ah1_w = (const float*)d_in[12];
  const float* ah1_b = (const float*)d_in[13];
  const float* ah2_w = (const float*)d_in[14];
  const float* ah2_b = (const float*)d_in[15];
  const float* f1w   = (const float*)d_in[16];
  const float* f1b   = (const float*)d_in[17];
  const float* f2w   = (const float*)d_in[18];
  const float* f2b_  = (const float*)d_in[19];
  const float* f3w   = (const float*)d_in[20];
  const float* f3b   = (const float*)d_in[21];
  float* out = (float*)d_out;

  char* ws = (char*)d_ws;
  float* part = (float*)ws;                                   // 8 MB
  float* rpart = (float*)(ws + 8388608);                      // 1 MB
  unsigned short* f1wb = (unsigned short*)(ws + 9437184);     // 256 KB
  unsigned short* f2wb = (unsigned short*)(ws + 9699328);     // 32 KB

  k_gemm1<<<dim3(32, KSPL, 4), 256, 0, stream>>>(x, ah1_w, part);
  k_gemm2<<<dim3(8, 8, 4), 256, 0, stream>>>(part, ah1_b, ah2_w, f1w, f2w,
                                             rpart, f1wb, f2wb);
  k_final<<<64, 512, 0, stream>>>(rpart, ah2_b, f1wb, f1b, f2wb, f2b_,
                                  f3w, f3b, out);
}